// Round 6
// baseline (1081.377 us; speedup 1.0000x reference)
//
#include <hip/hip_runtime.h>
#include <hip/hip_bf16.h>
#include <cstdint>

#define BATCH 128
#define SEQ   512
#define EMB   300
#define HID   100
#define G3    300
#define NCLS  20
#define NROWS (SEQ * BATCH)

// ---------------- threefry2x32 (JAX-compatible, verified round 1) ----------------
__host__ __device__ __forceinline__ void threefry2x32(uint32_t k0, uint32_t k1,
                                                      uint32_t x0, uint32_t x1,
                                                      uint32_t* o0, uint32_t* o1) {
  uint32_t ks2 = k0 ^ k1 ^ 0x1BD11BDAu;
  x0 += k0; x1 += k1;
#define TFR(r) { x0 += x1; x1 = (x1 << (r)) | (x1 >> (32 - (r))); x1 ^= x0; }
  TFR(13) TFR(15) TFR(26) TFR(6)  x0 += k1;  x1 += ks2 + 1u;
  TFR(17) TFR(29) TFR(16) TFR(24) x0 += ks2; x1 += k0 + 2u;
  TFR(13) TFR(15) TFR(26) TFR(6)  x0 += k0;  x1 += k1 + 3u;
  TFR(17) TFR(29) TFR(16) TFR(24) x0 += k1;  x1 += ks2 + 4u;
  TFR(13) TFR(15) TFR(26) TFR(6)  x0 += ks2; x1 += k0 + 5u;
#undef TFR
  *o0 = x0; *o1 = x1;
}

__device__ __forceinline__ uint32_t rand_bits32(uint32_t ka, uint32_t kb, uint32_t flat) {
  uint32_t a, b;
  threefry2x32(ka, kb, 0u, flat, &a, &b);
  return a ^ b;
}

// ---------------- K1 v3: double-buffered LDS, 1 barrier/chunk, pipelined gathers ----
// 128x128 tile, 8x8 per thread, K chunks of 16 (19 chunks, 304 padded).
// grid (512 s-tiles, 3 n-tiles), block 256.
__global__ __launch_bounds__(256) void k_gi3(const int* __restrict__ inputs,
                                             const float* __restrict__ emb,
                                             const float* __restrict__ w_ih,
                                             const float* __restrict__ b_ih,
                                             float* __restrict__ GI,
                                             uint32_t k1a, uint32_t k1b) {
  __shared__ float Xs[2][16][132];   // [buf][k][m]
  __shared__ float Ws[2][16][132];   // [buf][k][n]
  __shared__ int idxs[128];
  const int t = threadIdx.x;
  const int s = blockIdx.x;
  const int n0 = blockIdx.y * 128;
  const int tx = t & 15, ty = t >> 4;
  const int kq = t & 3;

  if (t < 128) idxs[t] = inputs[t * SEQ + s];

  float acc[8][8];
#pragma unroll
  for (int i = 0; i < 8; ++i)
#pragma unroll
    for (int j = 0; j < 8; ++j) acc[i][j] = 0.f;

  __syncthreads();   // idxs visible

  float4 xv[2], wv[2];
  // stage chunk kc into regs (global loads only — no threefry yet)
  auto stage = [&](int kc) {
#pragma unroll
    for (int h = 0; h < 2; ++h) {
      int row = (h ? (t + 256) : t) >> 2;   // 0..127
      int e0 = kc + kq * 4;
      xv[h] = make_float4(0.f, 0.f, 0.f, 0.f);
      wv[h] = make_float4(0.f, 0.f, 0.f, 0.f);
      if (e0 < 300) {
        xv[h] = *(const float4*)(emb + (size_t)idxs[row] * EMB + e0);
        int n = n0 + row;
        if (n < 300) wv[h] = *(const float4*)(w_ih + (size_t)n * EMB + e0);
      }
    }
  };
  // apply dropout1 + commit regs to LDS buffer
  auto commit = [&](int buf, int kc) {
#pragma unroll
    for (int h = 0; h < 2; ++h) {
      int row = (h ? (t + 256) : t) >> 2;
      int e0 = kc + kq * 4;
      float4 x = xv[h];
      if (e0 < 300) {
        uint32_t base = (uint32_t)((row * SEQ + s) * EMB + e0);
        x.x = (rand_bits32(k1a, k1b, base + 0u) >> 31) ? 0.f : x.x * 2.f;
        x.y = (rand_bits32(k1a, k1b, base + 1u) >> 31) ? 0.f : x.y * 2.f;
        x.z = (rand_bits32(k1a, k1b, base + 2u) >> 31) ? 0.f : x.z * 2.f;
        x.w = (rand_bits32(k1a, k1b, base + 3u) >> 31) ? 0.f : x.w * 2.f;
      }
      Xs[buf][kq * 4 + 0][row] = x.x;
      Xs[buf][kq * 4 + 1][row] = x.y;
      Xs[buf][kq * 4 + 2][row] = x.z;
      Xs[buf][kq * 4 + 3][row] = x.w;
      float4 w = wv[h];
      Ws[buf][kq * 4 + 0][row] = w.x;
      Ws[buf][kq * 4 + 1][row] = w.y;
      Ws[buf][kq * 4 + 2][row] = w.z;
      Ws[buf][kq * 4 + 3][row] = w.w;
    }
  };

  stage(0);
  commit(0, 0);
  __syncthreads();

  for (int c = 0; c < 19; ++c) {
    const int cur = c & 1;
    if (c + 1 < 19) stage((c + 1) * 16);   // issue loads; drained AFTER the FMA block
#pragma unroll
    for (int k = 0; k < 16; ++k) {
      float4 xa = *(const float4*)&Xs[cur][k][ty * 4];
      float4 xb = *(const float4*)&Xs[cur][k][64 + ty * 4];
      float4 wa = *(const float4*)&Ws[cur][k][tx * 4];
      float4 wb = *(const float4*)&Ws[cur][k][64 + tx * 4];
      float xs8[8] = {xa.x, xa.y, xa.z, xa.w, xb.x, xb.y, xb.z, xb.w};
      float ws8[8] = {wa.x, wa.y, wa.z, wa.w, wb.x, wb.y, wb.z, wb.w};
#pragma unroll
      for (int i = 0; i < 8; ++i)
#pragma unroll
        for (int j = 0; j < 8; ++j) acc[i][j] = fmaf(xs8[i], ws8[j], acc[i][j]);
    }
    if (c + 1 < 19) commit(cur ^ 1, (c + 1) * 16);  // waitcnt lands here (covered)
    __syncthreads();   // single barrier per chunk
  }

#pragma unroll
  for (int i = 0; i < 8; ++i) {
    int m = (i < 4) ? (ty * 4 + i) : (64 + ty * 4 + (i - 4));
    size_t rbase = (size_t)(s * BATCH + m) * G3;
    int cA = n0 + tx * 4;
    int cB = n0 + 64 + tx * 4;
    if (cA < 300) {
      float4 o = make_float4(acc[i][0] + b_ih[cA], acc[i][1] + b_ih[cA + 1],
                             acc[i][2] + b_ih[cA + 2], acc[i][3] + b_ih[cA + 3]);
      *(float4*)(GI + rbase + cA) = o;
    }
    if (cB < 300) {
      float4 o = make_float4(acc[i][4] + b_ih[cB], acc[i][5] + b_ih[cB + 1],
                             acc[i][6] + b_ih[cB + 2], acc[i][7] + b_ih[cB + 3]);
      *(float4*)(GI + rbase + cB) = o;
    }
  }
}

// ---------------- K2 v5: v4 structure + global-traffic batched per 8 steps ----------
// 16 waves, k-slice q=wave>>1 (13/13/13/13/12/12/12/12), unit-group g=wave&1.
// Weights: 39 resident SSA scalars/thread (verified resident in round 5, VGPR=56).
// NEW: gi loads, threefry masks, and Hd stores are hoisted to per-8-step group
// boundaries so the compiler's `s_waitcnt vmcnt(0)` before each s_barrier stops
// draining fresh global ops every step (the round-5 stall).
__global__ __launch_bounds__(1024, 4) void k_rnn5(const float* __restrict__ GI,
                                                  const float* __restrict__ w_hh,
                                                  const float* __restrict__ b_hh,
                                                  float* __restrict__ Hd,
                                                  uint32_t k2a, uint32_t k2b) {
  __shared__ float4 part[8][104];   // [kslice][unit] = (r,z,n,pad)
  __shared__ float h_s[100];
  const int t = threadIdx.x, lane = t & 63, wave = t >> 6;
  const int q = wave >> 1, g = wave & 1;
  const int b = blockIdx.x;
  const int ulo = (lane < 36) ? lane : 35;
  const int u = g ? (64 + ulo) : lane;
  const bool dotstore = (g == 0) || (lane < 36);
  const int klo = (q < 4) ? q * 13 : 52 + (q - 4) * 12;

  const float* rowR = w_hh + (size_t)u * HID;
  const float* rowZ = w_hh + (size_t)(u + 100) * HID;
  const float* rowN = w_hh + (size_t)(u + 200) * HID;
  const float wr0 = rowR[klo + 0],  wr1 = rowR[klo + 1],  wr2 = rowR[klo + 2],
              wr3 = rowR[klo + 3],  wr4 = rowR[klo + 4],  wr5 = rowR[klo + 5],
              wr6 = rowR[klo + 6],  wr7 = rowR[klo + 7],  wr8 = rowR[klo + 8],
              wr9 = rowR[klo + 9],  wr10 = rowR[klo + 10], wr11 = rowR[klo + 11],
              wr12 = rowR[(klo + 12 < 100) ? (klo + 12) : 99];
  const float wz0 = rowZ[klo + 0],  wz1 = rowZ[klo + 1],  wz2 = rowZ[klo + 2],
              wz3 = rowZ[klo + 3],  wz4 = rowZ[klo + 4],  wz5 = rowZ[klo + 5],
              wz6 = rowZ[klo + 6],  wz7 = rowZ[klo + 7],  wz8 = rowZ[klo + 8],
              wz9 = rowZ[klo + 9],  wz10 = rowZ[klo + 10], wz11 = rowZ[klo + 11],
              wz12 = rowZ[(klo + 12 < 100) ? (klo + 12) : 99];
  const float wn0 = rowN[klo + 0],  wn1 = rowN[klo + 1],  wn2 = rowN[klo + 2],
              wn3 = rowN[klo + 3],  wn4 = rowN[klo + 4],  wn5 = rowN[klo + 5],
              wn6 = rowN[klo + 6],  wn7 = rowN[klo + 7],  wn8 = rowN[klo + 8],
              wn9 = rowN[klo + 9],  wn10 = rowN[klo + 10], wn11 = rowN[klo + 11],
              wn12 = rowN[(klo + 12 < 100) ? (klo + 12) : 99];

  const bool ew = (wave < 4) && (lane < 25);
  const int ue = wave * 25 + lane;   // 0..99 when ew
  float bR = 0.f, bZ = 0.f, bN = 0.f;
  if (ew) { bR = b_hh[ue]; bZ = b_hh[100 + ue]; bN = b_hh[200 + ue]; }

  if (t < 100) h_s[t] = 0.f;
  float hA = 0.f, hB = 0.f;
  __syncthreads();

#define RL(reg, L) __int_as_float(__builtin_amdgcn_readlane(__float_as_int(reg), (L)))
#define S1(HS, L, WR, WZ, WN) { float hk = RL(HS, L); \
    sR = fmaf(WR, hk, sR); sZ = fmaf(WZ, hk, sZ); sN = fmaf(WN, hk, sN); }
#define D12(HS, L0) \
  S1(HS, (L0) + 0,  wr0,  wz0,  wn0)  S1(HS, (L0) + 1,  wr1,  wz1,  wn1)  \
  S1(HS, (L0) + 2,  wr2,  wz2,  wn2)  S1(HS, (L0) + 3,  wr3,  wz3,  wn3)  \
  S1(HS, (L0) + 4,  wr4,  wz4,  wn4)  S1(HS, (L0) + 5,  wr5,  wz5,  wn5)  \
  S1(HS, (L0) + 6,  wr6,  wz6,  wn6)  S1(HS, (L0) + 7,  wr7,  wz7,  wn7)  \
  S1(HS, (L0) + 8,  wr8,  wz8,  wn8)  S1(HS, (L0) + 9,  wr9,  wz9,  wn9)  \
  S1(HS, (L0) + 10, wr10, wz10, wn10) S1(HS, (L0) + 11, wr11, wz11, wn11)
#define D13(HS, L0) D12(HS, L0) S1(HS, (L0) + 12, wr12, wz12, wn12)

  for (int sc = 0; sc < SEQ / 8; ++sc) {
    // ---- group header: ALL global reads + RNG for the next 8 steps ----
    float gR[8], gZ[8], gN[8], hd8[8];
    uint32_t msk[8];
    if (ew) {
#pragma unroll
      for (int ss = 0; ss < 8; ++ss) {
        int s = sc * 8 + ss;
        const float* gp = GI + (size_t)(s * BATCH + b) * G3;
        gR[ss] = gp[ue]; gZ[ss] = gp[100 + ue]; gN[ss] = gp[200 + ue];
        msk[ss] = rand_bits32(k2a, k2b, (uint32_t)((s * BATCH + b) * HID + ue));
      }
    }

#pragma unroll
    for (int ss = 0; ss < 8; ++ss) {
      float sR = 0.f, sZ = 0.f, sN = 0.f;
      switch (q) {   // wave-uniform; readlane lane indices are literals
        case 0: { D13(hA, 0)  } break;
        case 1: { D13(hA, 13) } break;
        case 2: { D13(hA, 26) } break;
        case 3: { D13(hA, 39) } break;
        case 4: { D12(hA, 52) } break;
        case 5: { D12(hB, 0)  } break;
        case 6: { D12(hB, 12) } break;
        case 7: { D12(hB, 24) } break;
      }
      if (dotstore) part[q][u] = make_float4(sR, sZ, sN, 0.f);
      __syncthreads();   // barrier 1: partials visible (LDS-only traffic this step)

      if (wave < 4) {
        if (lane < 25) {
          float4 p0 = part[0][ue], p1 = part[1][ue], p2 = part[2][ue], p3 = part[3][ue];
          float4 p4 = part[4][ue], p5 = part[5][ue], p6 = part[6][ue], p7 = part[7][ue];
          float hr = ((p0.x + p1.x) + (p2.x + p3.x)) + ((p4.x + p5.x) + (p6.x + p7.x)) + bR;
          float hz = ((p0.y + p1.y) + (p2.y + p3.y)) + ((p4.y + p5.y) + (p6.y + p7.y)) + bZ;
          float hn = ((p0.z + p1.z) + (p2.z + p3.z)) + ((p4.z + p5.z) + (p6.z + p7.z)) + bN;
          float r = 1.f / (1.f + __expf(-(gR[ss] + hr)));
          float z = 1.f / (1.f + __expf(-(gZ[ss] + hz)));
          float xn = gN[ss] + r * hn;
          float e2 = __expf(2.f * fabsf(xn));
          float n = copysignf(1.f - 2.f / (e2 + 1.f), xn);   // overflow-safe tanh
          float hprev = h_s[ue];
          float hnew = (1.f - z) * n + z * hprev;
          hd8[ss] = (msk[ss] >> 31) ? 0.f : hnew * 2.f;      // buffered, flushed later
          h_s[ue] = hnew;
        }
      }
      __syncthreads();   // barrier 2: h_s updated (LDS-only traffic this step)
      hA = h_s[lane];
      hB = h_s[64 + ulo];
    }

    // ---- group footer: flush 8 Hd values (drains at NEXT group's barrier 1) ----
    if (ew) {
      float* hp = Hd + (size_t)(b * SEQ + sc * 8) * HID + ue;
#pragma unroll
      for (int ss = 0; ss < 8; ++ss) hp[(size_t)ss * HID] = hd8[ss];
    }
  }
#undef D13
#undef D12
#undef S1
#undef RL
}

// ---------------- K3: logits + log_softmax [unchanged] ----------------
__global__ __launch_bounds__(64) void k_out(const float* __restrict__ Hd,
                                            const float* __restrict__ w_lin,
                                            const float* __restrict__ b_lin,
                                            float* __restrict__ out) {
  __shared__ float Wl[NCLS * HID];
  __shared__ float bl[NCLS];
  const int t = threadIdx.x;
  for (int i = t; i < NCLS * HID; i += 64) Wl[i] = w_lin[i];
  if (t < NCLS) bl[t] = b_lin[t];
  __syncthreads();

  const int r0 = (blockIdx.x * 64 + t) * 4;
  float acc[4][NCLS];
#pragma unroll
  for (int r = 0; r < 4; ++r)
#pragma unroll
    for (int c = 0; c < NCLS; ++c) acc[r][c] = bl[c];

  for (int k = 0; k < HID; k += 4) {
    float4 h0 = *(const float4*)(Hd + (size_t)(r0 + 0) * HID + k);
    float4 h1 = *(const float4*)(Hd + (size_t)(r0 + 1) * HID + k);
    float4 h2 = *(const float4*)(Hd + (size_t)(r0 + 2) * HID + k);
    float4 h3 = *(const float4*)(Hd + (size_t)(r0 + 3) * HID + k);
#pragma unroll
    for (int c = 0; c < NCLS; ++c) {
      float4 w4 = *(const float4*)&Wl[c * HID + k];
      acc[0][c] += h0.x * w4.x + h0.y * w4.y + h0.z * w4.z + h0.w * w4.w;
      acc[1][c] += h1.x * w4.x + h1.y * w4.y + h1.z * w4.z + h1.w * w4.w;
      acc[2][c] += h2.x * w4.x + h2.y * w4.y + h2.z * w4.z + h2.w * w4.w;
      acc[3][c] += h3.x * w4.x + h3.y * w4.y + h3.z * w4.z + h3.w * w4.w;
    }
  }

  float lse[4];
#pragma unroll
  for (int r = 0; r < 4; ++r) {
    float mx = acc[r][0];
#pragma unroll
    for (int c = 1; c < NCLS; ++c) mx = fmaxf(mx, acc[r][c]);
    float se = 0.f;
#pragma unroll
    for (int c = 0; c < NCLS; ++c) se += __expf(acc[r][c] - mx);
    lse[r] = mx + __logf(se);
  }
  const int b = r0 >> 9, s0 = r0 & 511;
#pragma unroll
  for (int c = 0; c < NCLS; ++c) {
    float4 o = make_float4(acc[0][c] - lse[0], acc[1][c] - lse[1],
                           acc[2][c] - lse[2], acc[3][c] - lse[3]);
    *(float4*)(out + (size_t)(b * NCLS + c) * SEQ + s0) = o;
  }
}

// ---------------- host ----------------
extern "C" void kernel_launch(void* const* d_in, const int* in_sizes, int n_in,
                              void* d_out, int out_size, void* d_ws, size_t ws_size,
                              hipStream_t stream) {
  const int*   inputs = (const int*)d_in[0];
  const float* emb    = (const float*)d_in[1];
  const float* w_ih   = (const float*)d_in[2];
  const float* w_hh   = (const float*)d_in[3];
  const float* b_ih   = (const float*)d_in[4];
  const float* b_hh   = (const float*)d_in[5];
  const float* w_lin  = (const float*)d_in[6];
  const float* b_lin  = (const float*)d_in[7];
  float* out = (float*)d_out;

  float* GI = (float*)d_ws;                    // 65536*300 f32 = 78.6 MB
  float* Hd = GI + (size_t)NROWS * G3;         // 65536*100 f32 = 26.2 MB

  uint32_t dk1a, dk1b, dk2a, dk2b;
  threefry2x32(0u, 42u, 0u, 0u, &dk1a, &dk1b);
  threefry2x32(0u, 42u, 0u, 1u, &dk2a, &dk2b);

  k_gi3<<<dim3(512, 3), 256, 0, stream>>>(inputs, emb, w_ih, b_ih, GI, dk1a, dk1b);
  k_rnn5<<<BATCH, 1024, 0, stream>>>(GI, w_hh, b_hh, Hd, dk2a, dk2b);
  k_out<<<256, 64, 0, stream>>>(Hd, w_lin, b_lin, out);
}

// Round 7
// 1001.706 us; speedup vs baseline: 1.0795x; 1.0795x over previous
//
#include <hip/hip_runtime.h>
#include <hip/hip_bf16.h>
#include <cstdint>

#define BATCH 128
#define SEQ   512
#define EMB   300
#define HID   100
#define G3    300
#define NCLS  20
#define NROWS (SEQ * BATCH)

// ---------------- threefry2x32 (JAX-compatible, verified round 1) ----------------
__host__ __device__ __forceinline__ void threefry2x32(uint32_t k0, uint32_t k1,
                                                      uint32_t x0, uint32_t x1,
                                                      uint32_t* o0, uint32_t* o1) {
  uint32_t ks2 = k0 ^ k1 ^ 0x1BD11BDAu;
  x0 += k0; x1 += k1;
#define TFR(r) { x0 += x1; x1 = (x1 << (r)) | (x1 >> (32 - (r))); x1 ^= x0; }
  TFR(13) TFR(15) TFR(26) TFR(6)  x0 += k1;  x1 += ks2 + 1u;
  TFR(17) TFR(29) TFR(16) TFR(24) x0 += ks2; x1 += k0 + 2u;
  TFR(13) TFR(15) TFR(26) TFR(6)  x0 += k0;  x1 += k1 + 3u;
  TFR(17) TFR(29) TFR(16) TFR(24) x0 += k1;  x1 += ks2 + 4u;
  TFR(13) TFR(15) TFR(26) TFR(6)  x0 += ks2; x1 += k0 + 5u;
#undef TFR
  *o0 = x0; *o1 = x1;
}

__device__ __forceinline__ uint32_t rand_bits32(uint32_t ka, uint32_t kb, uint32_t flat) {
  uint32_t a, b;
  threefry2x32(ka, kb, 0u, flat, &a, &b);
  return a ^ b;
}

// ---------------- K1: GI = dropout1(emb[idx]) @ w_ih^T + b_ih ----------------
// [REVERTED to round-5's k_gi2 — k_gi3's double-buffer regressed ~110 µs
//  (stage regs held across the FMA block -> pressure/scratch).]
__global__ __launch_bounds__(256) void k_gi2(const int* __restrict__ inputs,
                                             const float* __restrict__ emb,
                                             const float* __restrict__ w_ih,
                                             const float* __restrict__ b_ih,
                                             float* __restrict__ GI,
                                             uint32_t k1a, uint32_t k1b) {
  __shared__ float Xs[16][132];
  __shared__ float Ws[16][132];
  __shared__ int idxs[128];
  const int t = threadIdx.x;
  const int s = blockIdx.x;
  const int n0 = blockIdx.y * 128;
  const int tx = t & 15, ty = t >> 4;

  if (t < 128) idxs[t] = inputs[t * SEQ + s];

  float acc[8][8];
#pragma unroll
  for (int i = 0; i < 8; ++i)
#pragma unroll
    for (int j = 0; j < 8; ++j) acc[i][j] = 0.f;

  __syncthreads();

  for (int kc = 0; kc < 304; kc += 16) {
#pragma unroll
    for (int half = 0; half < 2; ++half) {
      int fi = t + half * 256;
      int row = fi >> 2;
      int kq = fi & 3;
      int e0 = kc + kq * 4;
      float4 xv = make_float4(0.f, 0.f, 0.f, 0.f);
      if (e0 < 300) {
        xv = *(const float4*)(emb + (size_t)idxs[row] * EMB + e0);
        uint32_t base = (uint32_t)((row * SEQ + s) * EMB + e0);
        xv.x = (rand_bits32(k1a, k1b, base + 0u) >> 31) ? 0.f : xv.x * 2.f;
        xv.y = (rand_bits32(k1a, k1b, base + 1u) >> 31) ? 0.f : xv.y * 2.f;
        xv.z = (rand_bits32(k1a, k1b, base + 2u) >> 31) ? 0.f : xv.z * 2.f;
        xv.w = (rand_bits32(k1a, k1b, base + 3u) >> 31) ? 0.f : xv.w * 2.f;
      }
      Xs[kq * 4 + 0][row] = xv.x;
      Xs[kq * 4 + 1][row] = xv.y;
      Xs[kq * 4 + 2][row] = xv.z;
      Xs[kq * 4 + 3][row] = xv.w;
      int n = n0 + row;
      float4 wv = make_float4(0.f, 0.f, 0.f, 0.f);
      if (e0 < 300 && n < 300) wv = *(const float4*)(w_ih + (size_t)n * EMB + e0);
      Ws[kq * 4 + 0][row] = wv.x;
      Ws[kq * 4 + 1][row] = wv.y;
      Ws[kq * 4 + 2][row] = wv.z;
      Ws[kq * 4 + 3][row] = wv.w;
    }
    __syncthreads();
#pragma unroll
    for (int k = 0; k < 16; ++k) {
      float4 xa = *(const float4*)&Xs[k][ty * 4];
      float4 xb = *(const float4*)&Xs[k][64 + ty * 4];
      float4 wa = *(const float4*)&Ws[k][tx * 4];
      float4 wb = *(const float4*)&Ws[k][64 + tx * 4];
      float xs8[8] = {xa.x, xa.y, xa.z, xa.w, xb.x, xb.y, xb.z, xb.w};
      float ws8[8] = {wa.x, wa.y, wa.z, wa.w, wb.x, wb.y, wb.z, wb.w};
#pragma unroll
      for (int i = 0; i < 8; ++i)
#pragma unroll
        for (int j = 0; j < 8; ++j) acc[i][j] = fmaf(xs8[i], ws8[j], acc[i][j]);
    }
    __syncthreads();
  }

#pragma unroll
  for (int i = 0; i < 8; ++i) {
    int m = (i < 4) ? (ty * 4 + i) : (64 + ty * 4 + (i - 4));
    size_t rbase = (size_t)(s * BATCH + m) * G3;
    int cA = n0 + tx * 4;
    int cB = n0 + 64 + tx * 4;
    if (cA < 300) {
      float4 o = make_float4(acc[i][0] + b_ih[cA], acc[i][1] + b_ih[cA + 1],
                             acc[i][2] + b_ih[cA + 2], acc[i][3] + b_ih[cA + 3]);
      *(float4*)(GI + rbase + cA) = o;
    }
    if (cB < 300) {
      float4 o = make_float4(acc[i][4] + b_ih[cB], acc[i][5] + b_ih[cB + 1],
                             acc[i][6] + b_ih[cB + 2], acc[i][7] + b_ih[cB + 3]);
      *(float4*)(GI + rbase + cB) = o;
    }
  }
}

// ---------------- K2 v6: v4 skeleton + dropout/store offloaded to waves 4-7 ----------
// 16 waves; dot identical to v4 (VGPR=56 proven). Elementwise (waves 0-3,
// lanes<25) now writes raw hnew to LDS ring hb[parity][ss][ue] — NO threefry,
// NO global store between barriers. Waves 4-7 flush the previous 8-step group
// (threefry + dropout scale + Hd store) at each group boundary, off the
// critical path. Only steady-state global ops inside the barrier region are
// the 3 gi loads, issued a full dot-phase before their consuming barrier.
__global__ __launch_bounds__(1024, 4) void k_rnn6(const float* __restrict__ GI,
                                                  const float* __restrict__ w_hh,
                                                  const float* __restrict__ b_hh,
                                                  float* __restrict__ Hd,
                                                  uint32_t k2a, uint32_t k2b) {
  __shared__ float4 part[8][104];     // [kslice][unit] = (r,z,n,pad)
  __shared__ float h_s[100];
  __shared__ float hb[2][8][100];     // raw hnew ring, parity = (s>>3)&1
  const int t = threadIdx.x, lane = t & 63, wave = t >> 6;
  const int q = wave >> 1, g = wave & 1;
  const int b = blockIdx.x;
  const int ulo = (lane < 36) ? lane : 35;
  const int u = g ? (64 + ulo) : lane;
  const bool dotstore = (g == 0) || (lane < 36);
  const int klo = (q < 4) ? q * 13 : 52 + (q - 4) * 12;

  const float* rowR = w_hh + (size_t)u * HID;
  const float* rowZ = w_hh + (size_t)(u + 100) * HID;
  const float* rowN = w_hh + (size_t)(u + 200) * HID;
  const float wr0 = rowR[klo + 0],  wr1 = rowR[klo + 1],  wr2 = rowR[klo + 2],
              wr3 = rowR[klo + 3],  wr4 = rowR[klo + 4],  wr5 = rowR[klo + 5],
              wr6 = rowR[klo + 6],  wr7 = rowR[klo + 7],  wr8 = rowR[klo + 8],
              wr9 = rowR[klo + 9],  wr10 = rowR[klo + 10], wr11 = rowR[klo + 11],
              wr12 = rowR[(klo + 12 < 100) ? (klo + 12) : 99];
  const float wz0 = rowZ[klo + 0],  wz1 = rowZ[klo + 1],  wz2 = rowZ[klo + 2],
              wz3 = rowZ[klo + 3],  wz4 = rowZ[klo + 4],  wz5 = rowZ[klo + 5],
              wz6 = rowZ[klo + 6],  wz7 = rowZ[klo + 7],  wz8 = rowZ[klo + 8],
              wz9 = rowZ[klo + 9],  wz10 = rowZ[klo + 10], wz11 = rowZ[klo + 11],
              wz12 = rowZ[(klo + 12 < 100) ? (klo + 12) : 99];
  const float wn0 = rowN[klo + 0],  wn1 = rowN[klo + 1],  wn2 = rowN[klo + 2],
              wn3 = rowN[klo + 3],  wn4 = rowN[klo + 4],  wn5 = rowN[klo + 5],
              wn6 = rowN[klo + 6],  wn7 = rowN[klo + 7],  wn8 = rowN[klo + 8],
              wn9 = rowN[klo + 9],  wn10 = rowN[klo + 10], wn11 = rowN[klo + 11],
              wn12 = rowN[(klo + 12 < 100) ? (klo + 12) : 99];

  const bool ew = (wave < 4) && (lane < 25);
  const int ue = wave * 25 + lane;   // 0..99 when ew
  float bR = 0.f, bZ = 0.f, bN = 0.f, gcR = 0.f, gcZ = 0.f, gcN = 0.f;
  if (ew) {
    bR = b_hh[ue]; bZ = b_hh[100 + ue]; bN = b_hh[200 + ue];
    const float* g0 = GI + (size_t)b * G3;
    gcR = g0[ue]; gcZ = g0[100 + ue]; gcN = g0[200 + ue];
  }
  const bool fl = (wave >= 4) && (wave < 8);
  const int fid = (wave - 4) * 64 + lane;   // 0..255 for flusher waves

  if (t < 100) h_s[t] = 0.f;
  float hA = 0.f, hB = 0.f;
  __syncthreads();

#define RL(reg, L) __int_as_float(__builtin_amdgcn_readlane(__float_as_int(reg), (L)))
#define S1(HS, L, WR, WZ, WN) { float hk = RL(HS, L); \
    sR = fmaf(WR, hk, sR); sZ = fmaf(WZ, hk, sZ); sN = fmaf(WN, hk, sN); }
#define D12(HS, L0) \
  S1(HS, (L0) + 0,  wr0,  wz0,  wn0)  S1(HS, (L0) + 1,  wr1,  wz1,  wn1)  \
  S1(HS, (L0) + 2,  wr2,  wz2,  wn2)  S1(HS, (L0) + 3,  wr3,  wz3,  wn3)  \
  S1(HS, (L0) + 4,  wr4,  wz4,  wn4)  S1(HS, (L0) + 5,  wr5,  wz5,  wn5)  \
  S1(HS, (L0) + 6,  wr6,  wz6,  wn6)  S1(HS, (L0) + 7,  wr7,  wz7,  wn7)  \
  S1(HS, (L0) + 8,  wr8,  wz8,  wn8)  S1(HS, (L0) + 9,  wr9,  wz9,  wn9)  \
  S1(HS, (L0) + 10, wr10, wz10, wn10) S1(HS, (L0) + 11, wr11, wz11, wn11)
#define D13(HS, L0) D12(HS, L0) S1(HS, (L0) + 12, wr12, wz12, wn12)

  for (int s = 0; s < SEQ; ++s) {
    // ---- group-boundary flush of the PREVIOUS 8 steps (waves 4-7 only) ----
    if (fl && (s & 7) == 0 && s > 0) {
      const int p = ((s >> 3) - 1) & 1;
      const int s0 = s - 8;
#pragma unroll
      for (int r = 0; r < 4; ++r) {
        int pp = fid + r * 256;           // 0..1023, use <800
        if (pp < 800) {
          int ss2 = pp / 100, uu2 = pp - (pp / 100) * 100;
          float hnew = hb[p][ss2][uu2];
          uint32_t m = rand_bits32(k2a, k2b,
                         (uint32_t)(((s0 + ss2) * BATCH + b) * HID + uu2));
          Hd[(size_t)(b * SEQ + s0 + ss2) * HID + uu2] = (m >> 31) ? 0.f : hnew * 2.f;
        }
      }
    }

    // prefetch next step's gi (consumed next iteration -> full dot of slack)
    float gnR = 0.f, gnZ = 0.f, gnN = 0.f;
    if (ew) {
      int sn = (s + 1 < SEQ) ? s + 1 : s;
      const float* gp = GI + (size_t)(sn * BATCH + b) * G3;
      gnR = gp[ue]; gnZ = gp[100 + ue]; gnN = gp[200 + ue];
    }

    float sR = 0.f, sZ = 0.f, sN = 0.f;
    switch (q) {   // wave-uniform; readlane lane indices are literals
      case 0: { D13(hA, 0)  } break;
      case 1: { D13(hA, 13) } break;
      case 2: { D13(hA, 26) } break;
      case 3: { D13(hA, 39) } break;
      case 4: { D12(hA, 52) } break;
      case 5: { D12(hB, 0)  } break;
      case 6: { D12(hB, 12) } break;
      case 7: { D12(hB, 24) } break;
    }
    if (dotstore) part[q][u] = make_float4(sR, sZ, sN, 0.f);
    __syncthreads();   // barrier 1: partials visible

    if (wave < 4) {
      if (lane < 25) {
        float4 p0 = part[0][ue], p1 = part[1][ue], p2 = part[2][ue], p3 = part[3][ue];
        float4 p4 = part[4][ue], p5 = part[5][ue], p6 = part[6][ue], p7 = part[7][ue];
        float hr = ((p0.x + p1.x) + (p2.x + p3.x)) + ((p4.x + p5.x) + (p6.x + p7.x)) + bR;
        float hz = ((p0.y + p1.y) + (p2.y + p3.y)) + ((p4.y + p5.y) + (p6.y + p7.y)) + bZ;
        float hn = ((p0.z + p1.z) + (p2.z + p3.z)) + ((p4.z + p5.z) + (p6.z + p7.z)) + bN;
        float r = 1.f / (1.f + __expf(-(gcR + hr)));
        float z = 1.f / (1.f + __expf(-(gcZ + hz)));
        float xn = gcN + r * hn;
        float e2 = __expf(2.f * fabsf(xn));
        float n = copysignf(1.f - 2.f / (e2 + 1.f), xn);   // overflow-safe tanh
        float hprev = h_s[ue];
        float hnew = (1.f - z) * n + z * hprev;
        h_s[ue] = hnew;
        hb[(s >> 3) & 1][s & 7][ue] = hnew;    // raw hnew; dropout applied by flushers
      }
    }
    __syncthreads();   // barrier 2: h_s + hb updated (LDS-only traffic)
    hA = h_s[lane];
    hB = h_s[64 + ulo];
    gcR = gnR; gcZ = gnZ; gcN = gnN;
  }

  // ---- final flush: last group (s0 = 504, parity = (63)&1 = 1) ----
  if (fl) {
#pragma unroll
    for (int r = 0; r < 4; ++r) {
      int pp = fid + r * 256;
      if (pp < 800) {
        int ss2 = pp / 100, uu2 = pp - (pp / 100) * 100;
        float hnew = hb[1][ss2][uu2];
        uint32_t m = rand_bits32(k2a, k2b,
                       (uint32_t)(((504 + ss2) * BATCH + b) * HID + uu2));
        Hd[(size_t)(b * SEQ + 504 + ss2) * HID + uu2] = (m >> 31) ? 0.f : hnew * 2.f;
      }
    }
  }
#undef D13
#undef D12
#undef S1
#undef RL
}

// ---------------- K3: logits + log_softmax [unchanged] ----------------
__global__ __launch_bounds__(64) void k_out(const float* __restrict__ Hd,
                                            const float* __restrict__ w_lin,
                                            const float* __restrict__ b_lin,
                                            float* __restrict__ out) {
  __shared__ float Wl[NCLS * HID];
  __shared__ float bl[NCLS];
  const int t = threadIdx.x;
  for (int i = t; i < NCLS * HID; i += 64) Wl[i] = w_lin[i];
  if (t < NCLS) bl[t] = b_lin[t];
  __syncthreads();

  const int r0 = (blockIdx.x * 64 + t) * 4;
  float acc[4][NCLS];
#pragma unroll
  for (int r = 0; r < 4; ++r)
#pragma unroll
    for (int c = 0; c < NCLS; ++c) acc[r][c] = bl[c];

  for (int k = 0; k < HID; k += 4) {
    float4 h0 = *(const float4*)(Hd + (size_t)(r0 + 0) * HID + k);
    float4 h1 = *(const float4*)(Hd + (size_t)(r0 + 1) * HID + k);
    float4 h2 = *(const float4*)(Hd + (size_t)(r0 + 2) * HID + k);
    float4 h3 = *(const float4*)(Hd + (size_t)(r0 + 3) * HID + k);
#pragma unroll
    for (int c = 0; c < NCLS; ++c) {
      float4 w4 = *(const float4*)&Wl[c * HID + k];
      acc[0][c] += h0.x * w4.x + h0.y * w4.y + h0.z * w4.z + h0.w * w4.w;
      acc[1][c] += h1.x * w4.x + h1.y * w4.y + h1.z * w4.z + h1.w * w4.w;
      acc[2][c] += h2.x * w4.x + h2.y * w4.y + h2.z * w4.z + h2.w * w4.w;
      acc[3][c] += h3.x * w4.x + h3.y * w4.y + h3.z * w4.z + h3.w * w4.w;
    }
  }

  float lse[4];
#pragma unroll
  for (int r = 0; r < 4; ++r) {
    float mx = acc[r][0];
#pragma unroll
    for (int c = 1; c < NCLS; ++c) mx = fmaxf(mx, acc[r][c]);
    float se = 0.f;
#pragma unroll
    for (int c = 0; c < NCLS; ++c) se += __expf(acc[r][c] - mx);
    lse[r] = mx + __logf(se);
  }
  const int b = r0 >> 9, s0 = r0 & 511;
#pragma unroll
  for (int c = 0; c < NCLS; ++c) {
    float4 o = make_float4(acc[0][c] - lse[0], acc[1][c] - lse[1],
                           acc[2][c] - lse[2], acc[3][c] - lse[3]);
    *(float4*)(out + (size_t)(b * NCLS + c) * SEQ + s0) = o;
  }
}

// ---------------- host ----------------
extern "C" void kernel_launch(void* const* d_in, const int* in_sizes, int n_in,
                              void* d_out, int out_size, void* d_ws, size_t ws_size,
                              hipStream_t stream) {
  const int*   inputs = (const int*)d_in[0];
  const float* emb    = (const float*)d_in[1];
  const float* w_ih   = (const float*)d_in[2];
  const float* w_hh   = (const float*)d_in[3];
  const float* b_ih   = (const float*)d_in[4];
  const float* b_hh   = (const float*)d_in[5];
  const float* w_lin  = (const float*)d_in[6];
  const float* b_lin  = (const float*)d_in[7];
  float* out = (float*)d_out;

  float* GI = (float*)d_ws;                    // 65536*300 f32 = 78.6 MB
  float* Hd = GI + (size_t)NROWS * G3;         // 65536*100 f32 = 26.2 MB

  uint32_t dk1a, dk1b, dk2a, dk2b;
  threefry2x32(0u, 42u, 0u, 0u, &dk1a, &dk1b);
  threefry2x32(0u, 42u, 0u, 1u, &dk2a, &dk2b);

  k_gi2<<<dim3(512, 3), 256, 0, stream>>>(inputs, emb, w_ih, b_ih, GI, dk1a, dk1b);
  k_rnn6<<<BATCH, 1024, 0, stream>>>(GI, w_hh, b_hh, Hd, dk2a, dk2b);
  k_out<<<256, 64, 0, stream>>>(Hd, w_lin, b_lin, out);
}

// Round 8
// 809.730 us; speedup vs baseline: 1.3355x; 1.2371x over previous
//
#include <hip/hip_runtime.h>
#include <hip/hip_bf16.h>
#include <cstdint>

#define BATCH 128
#define SEQ   512
#define EMB   300
#define HID   100
#define G3    300
#define NCLS  20
#define NROWS (SEQ * BATCH)

#define M1_WORDS 614400   // 128*512*300 / 32
#define M2_WORDS 204800   // 512*128*100 / 32

// ---------------- threefry2x32 (JAX-compatible, verified round 1) ----------------
__host__ __device__ __forceinline__ void threefry2x32(uint32_t k0, uint32_t k1,
                                                      uint32_t x0, uint32_t x1,
                                                      uint32_t* o0, uint32_t* o1) {
  uint32_t ks2 = k0 ^ k1 ^ 0x1BD11BDAu;
  x0 += k0; x1 += k1;
#define TFR(r) { x0 += x1; x1 = (x1 << (r)) | (x1 >> (32 - (r))); x1 ^= x0; }
  TFR(13) TFR(15) TFR(26) TFR(6)  x0 += k1;  x1 += ks2 + 1u;
  TFR(17) TFR(29) TFR(16) TFR(24) x0 += ks2; x1 += k0 + 2u;
  TFR(13) TFR(15) TFR(26) TFR(6)  x0 += k0;  x1 += k1 + 3u;
  TFR(17) TFR(29) TFR(16) TFR(24) x0 += k1;  x1 += ks2 + 4u;
  TFR(13) TFR(15) TFR(26) TFR(6)  x0 += ks2; x1 += k0 + 5u;
#undef TFR
  *o0 = x0; *o1 = x1;
}

__device__ __forceinline__ uint32_t rand_bits32(uint32_t ka, uint32_t kb, uint32_t flat) {
  uint32_t a, b;
  threefry2x32(ka, kb, 0u, flat, &a, &b);
  return a ^ b;
}

// ---------------- K0: precompute bit-packed dropout masks ----------------
// word i<M1_WORDS: mask1 (key dk1, flat [B,S,E]); else mask2 (key dk2, flat [S,B,H]).
// bit j of word w = KEEP bit for flat = 32*w + j  (keep iff bits>>31 == 0).
// Boundary is block-aligned (614400/256 = 2400) -> wave-uniform key selection.
__global__ __launch_bounds__(256) void k_mask(uint32_t* __restrict__ M1w,
                                              uint32_t* __restrict__ M2w,
                                              uint32_t k1a, uint32_t k1b,
                                              uint32_t k2a, uint32_t k2b) {
  const int i = blockIdx.x * 256 + threadIdx.x;
  uint32_t ka, kb, base;
  uint32_t* dst;
  if (i < M1_WORDS) { ka = k1a; kb = k1b; base = (uint32_t)i * 32u; dst = M1w + i; }
  else { ka = k2a; kb = k2b; base = (uint32_t)(i - M1_WORDS) * 32u; dst = M2w + (i - M1_WORDS); }
  uint32_t w = 0u;
#pragma unroll
  for (int j = 0; j < 32; ++j) {
    uint32_t bits = rand_bits32(ka, kb, base + (uint32_t)j);
    w |= ((~bits) >> 31) << j;
  }
  *dst = w;
}

// ---------------- K1 v4: k_gi2 with threefry replaced by mask-byte loads ----------
// 128x128 tile, 8x8 per thread; grid (512 s-tiles, 3 n-tiles), block 256.
__global__ __launch_bounds__(256) void k_gi4(const int* __restrict__ inputs,
                                             const float* __restrict__ emb,
                                             const float* __restrict__ w_ih,
                                             const float* __restrict__ b_ih,
                                             const uint8_t* __restrict__ M1,
                                             float* __restrict__ GI) {
  __shared__ float Xs[16][132];
  __shared__ float Ws[16][132];
  __shared__ int idxs[128];
  const int t = threadIdx.x;
  const int s = blockIdx.x;
  const int n0 = blockIdx.y * 128;
  const int tx = t & 15, ty = t >> 4;

  if (t < 128) idxs[t] = inputs[t * SEQ + s];

  float acc[8][8];
#pragma unroll
  for (int i = 0; i < 8; ++i)
#pragma unroll
    for (int j = 0; j < 8; ++j) acc[i][j] = 0.f;

  __syncthreads();

  for (int kc = 0; kc < 304; kc += 16) {
#pragma unroll
    for (int half = 0; half < 2; ++half) {
      int fi = t + half * 256;
      int row = fi >> 2;
      int kq = fi & 3;
      int e0 = kc + kq * 4;
      float4 xv = make_float4(0.f, 0.f, 0.f, 0.f);
      if (e0 < 300) {
        xv = *(const float4*)(emb + (size_t)idxs[row] * EMB + e0);
        // keep-bits from precomputed mask: base%8 in {0,4} (300%8==4, e0%4==0)
        uint32_t base = (uint32_t)((row * SEQ + s) * EMB + e0);
        uint32_t nib = (uint32_t)(M1[base >> 3]) >> (base & 7);
        xv.x = (nib & 1u) ? xv.x * 2.f : 0.f;
        xv.y = (nib & 2u) ? xv.y * 2.f : 0.f;
        xv.z = (nib & 4u) ? xv.z * 2.f : 0.f;
        xv.w = (nib & 8u) ? xv.w * 2.f : 0.f;
      }
      Xs[kq * 4 + 0][row] = xv.x;
      Xs[kq * 4 + 1][row] = xv.y;
      Xs[kq * 4 + 2][row] = xv.z;
      Xs[kq * 4 + 3][row] = xv.w;
      int n = n0 + row;
      float4 wv = make_float4(0.f, 0.f, 0.f, 0.f);
      if (e0 < 300 && n < 300) wv = *(const float4*)(w_ih + (size_t)n * EMB + e0);
      Ws[kq * 4 + 0][row] = wv.x;
      Ws[kq * 4 + 1][row] = wv.y;
      Ws[kq * 4 + 2][row] = wv.z;
      Ws[kq * 4 + 3][row] = wv.w;
    }
    __syncthreads();
#pragma unroll
    for (int k = 0; k < 16; ++k) {
      float4 xa = *(const float4*)&Xs[k][ty * 4];
      float4 xb = *(const float4*)&Xs[k][64 + ty * 4];
      float4 wa = *(const float4*)&Ws[k][tx * 4];
      float4 wb = *(const float4*)&Ws[k][64 + tx * 4];
      float xs8[8] = {xa.x, xa.y, xa.z, xa.w, xb.x, xb.y, xb.z, xb.w};
      float ws8[8] = {wa.x, wa.y, wa.z, wa.w, wb.x, wb.y, wb.z, wb.w};
#pragma unroll
      for (int i = 0; i < 8; ++i)
#pragma unroll
        for (int j = 0; j < 8; ++j) acc[i][j] = fmaf(xs8[i], ws8[j], acc[i][j]);
    }
    __syncthreads();
  }

#pragma unroll
  for (int i = 0; i < 8; ++i) {
    int m = (i < 4) ? (ty * 4 + i) : (64 + ty * 4 + (i - 4));
    size_t rbase = (size_t)(s * BATCH + m) * G3;
    int cA = n0 + tx * 4;
    int cB = n0 + 64 + tx * 4;
    if (cA < 300) {
      float4 o = make_float4(acc[i][0] + b_ih[cA], acc[i][1] + b_ih[cA + 1],
                             acc[i][2] + b_ih[cA + 2], acc[i][3] + b_ih[cA + 3]);
      *(float4*)(GI + rbase + cA) = o;
    }
    if (cB < 300) {
      float4 o = make_float4(acc[i][4] + b_ih[cB], acc[i][5] + b_ih[cB + 1],
                             acc[i][6] + b_ih[cB + 2], acc[i][7] + b_ih[cB + 3]);
      *(float4*)(GI + rbase + cB) = o;
    }
  }
}

// ---------------- K2 v7: EXACT v4 skeleton (best, 537 µs) + mask byte for dropout2 ----
__global__ __launch_bounds__(1024, 4) void k_rnn7(const float* __restrict__ GI,
                                                  const float* __restrict__ w_hh,
                                                  const float* __restrict__ b_hh,
                                                  const uint8_t* __restrict__ M2,
                                                  float* __restrict__ Hd) {
  __shared__ float4 part[8][104];
  __shared__ float h_s[100];
  const int t = threadIdx.x, lane = t & 63, wave = t >> 6;
  const int q = wave >> 1, g = wave & 1;
  const int b = blockIdx.x;
  const int ulo = (lane < 36) ? lane : 35;
  const int u = g ? (64 + ulo) : lane;
  const bool dotstore = (g == 0) || (lane < 36);
  const int klo = (q < 4) ? q * 13 : 52 + (q - 4) * 12;

  const float* rowR = w_hh + (size_t)u * HID;
  const float* rowZ = w_hh + (size_t)(u + 100) * HID;
  const float* rowN = w_hh + (size_t)(u + 200) * HID;
  const float wr0 = rowR[klo + 0],  wr1 = rowR[klo + 1],  wr2 = rowR[klo + 2],
              wr3 = rowR[klo + 3],  wr4 = rowR[klo + 4],  wr5 = rowR[klo + 5],
              wr6 = rowR[klo + 6],  wr7 = rowR[klo + 7],  wr8 = rowR[klo + 8],
              wr9 = rowR[klo + 9],  wr10 = rowR[klo + 10], wr11 = rowR[klo + 11],
              wr12 = rowR[(klo + 12 < 100) ? (klo + 12) : 99];
  const float wz0 = rowZ[klo + 0],  wz1 = rowZ[klo + 1],  wz2 = rowZ[klo + 2],
              wz3 = rowZ[klo + 3],  wz4 = rowZ[klo + 4],  wz5 = rowZ[klo + 5],
              wz6 = rowZ[klo + 6],  wz7 = rowZ[klo + 7],  wz8 = rowZ[klo + 8],
              wz9 = rowZ[klo + 9],  wz10 = rowZ[klo + 10], wz11 = rowZ[klo + 11],
              wz12 = rowZ[(klo + 12 < 100) ? (klo + 12) : 99];
  const float wn0 = rowN[klo + 0],  wn1 = rowN[klo + 1],  wn2 = rowN[klo + 2],
              wn3 = rowN[klo + 3],  wn4 = rowN[klo + 4],  wn5 = rowN[klo + 5],
              wn6 = rowN[klo + 6],  wn7 = rowN[klo + 7],  wn8 = rowN[klo + 8],
              wn9 = rowN[klo + 9],  wn10 = rowN[klo + 10], wn11 = rowN[klo + 11],
              wn12 = rowN[(klo + 12 < 100) ? (klo + 12) : 99];

  const bool ew = (wave < 4) && (lane < 25);
  const int ue = wave * 25 + lane;   // 0..99 when ew
  float bR = 0.f, bZ = 0.f, bN = 0.f, gcR = 0.f, gcZ = 0.f, gcN = 0.f;
  uint8_t mc = 0;
  if (ew) {
    bR = b_hh[ue]; bZ = b_hh[100 + ue]; bN = b_hh[200 + ue];
    const float* g0 = GI + (size_t)b * G3;
    gcR = g0[ue]; gcZ = g0[100 + ue]; gcN = g0[200 + ue];
    mc = M2[(uint32_t)(b * HID + ue) >> 3];
  }

  if (t < 100) h_s[t] = 0.f;
  float hA = 0.f, hB = 0.f;
  __syncthreads();

#define RL(reg, L) __int_as_float(__builtin_amdgcn_readlane(__float_as_int(reg), (L)))
#define S1(HS, L, WR, WZ, WN) { float hk = RL(HS, L); \
    sR = fmaf(WR, hk, sR); sZ = fmaf(WZ, hk, sZ); sN = fmaf(WN, hk, sN); }
#define D12(HS, L0) \
  S1(HS, (L0) + 0,  wr0,  wz0,  wn0)  S1(HS, (L0) + 1,  wr1,  wz1,  wn1)  \
  S1(HS, (L0) + 2,  wr2,  wz2,  wn2)  S1(HS, (L0) + 3,  wr3,  wz3,  wn3)  \
  S1(HS, (L0) + 4,  wr4,  wz4,  wn4)  S1(HS, (L0) + 5,  wr5,  wz5,  wn5)  \
  S1(HS, (L0) + 6,  wr6,  wz6,  wn6)  S1(HS, (L0) + 7,  wr7,  wz7,  wn7)  \
  S1(HS, (L0) + 8,  wr8,  wz8,  wn8)  S1(HS, (L0) + 9,  wr9,  wz9,  wn9)  \
  S1(HS, (L0) + 10, wr10, wz10, wn10) S1(HS, (L0) + 11, wr11, wz11, wn11)
#define D13(HS, L0) D12(HS, L0) S1(HS, (L0) + 12, wr12, wz12, wn12)

  for (int s = 0; s < SEQ; ++s) {
    // prefetch next step's gi + mask byte (consumed next iteration)
    float gnR = 0.f, gnZ = 0.f, gnN = 0.f;
    uint8_t mn = 0;
    if (ew) {
      int sn = (s + 1 < SEQ) ? s + 1 : s;
      const float* gp = GI + (size_t)(sn * BATCH + b) * G3;
      gnR = gp[ue]; gnZ = gp[100 + ue]; gnN = gp[200 + ue];
      mn = M2[(uint32_t)((sn * BATCH + b) * HID + ue) >> 3];
    }

    float sR = 0.f, sZ = 0.f, sN = 0.f;
    switch (q) {   // wave-uniform; readlane lane indices are literals
      case 0: { D13(hA, 0)  } break;
      case 1: { D13(hA, 13) } break;
      case 2: { D13(hA, 26) } break;
      case 3: { D13(hA, 39) } break;
      case 4: { D12(hA, 52) } break;
      case 5: { D12(hB, 0)  } break;
      case 6: { D12(hB, 12) } break;
      case 7: { D12(hB, 24) } break;
    }
    if (dotstore) part[q][u] = make_float4(sR, sZ, sN, 0.f);
    __syncthreads();   // barrier 1: partials visible

    if (wave < 4) {
      if (lane < 25) {
        float4 p0 = part[0][ue], p1 = part[1][ue], p2 = part[2][ue], p3 = part[3][ue];
        float4 p4 = part[4][ue], p5 = part[5][ue], p6 = part[6][ue], p7 = part[7][ue];
        float hr = ((p0.x + p1.x) + (p2.x + p3.x)) + ((p4.x + p5.x) + (p6.x + p7.x)) + bR;
        float hz = ((p0.y + p1.y) + (p2.y + p3.y)) + ((p4.y + p5.y) + (p6.y + p7.y)) + bZ;
        float hn = ((p0.z + p1.z) + (p2.z + p3.z)) + ((p4.z + p5.z) + (p6.z + p7.z)) + bN;
        float r = 1.f / (1.f + __expf(-(gcR + hr)));
        float z = 1.f / (1.f + __expf(-(gcZ + hz)));
        float xn = gcN + r * hn;
        float e2 = __expf(2.f * fabsf(xn));
        float n = copysignf(1.f - 2.f / (e2 + 1.f), xn);   // overflow-safe tanh
        float hprev = h_s[ue];
        float hnew = (1.f - z) * n + z * hprev;
        uint32_t fl = (uint32_t)((s * BATCH + b) * HID + ue);
        float hd = ((mc >> (fl & 7)) & 1) ? hnew * 2.f : 0.f;   // precomputed keep bit
        Hd[(size_t)(b * SEQ + s) * HID + ue] = hd;
        h_s[ue] = hnew;
      }
    }
    __syncthreads();   // barrier 2: h_s updated
    hA = h_s[lane];
    hB = h_s[64 + ulo];
    gcR = gnR; gcZ = gnZ; gcN = gnN; mc = mn;
  }
#undef D13
#undef D12
#undef S1
#undef RL
}

// ---------------- K3: logits + log_softmax [unchanged] ----------------
__global__ __launch_bounds__(64) void k_out(const float* __restrict__ Hd,
                                            const float* __restrict__ w_lin,
                                            const float* __restrict__ b_lin,
                                            float* __restrict__ out) {
  __shared__ float Wl[NCLS * HID];
  __shared__ float bl[NCLS];
  const int t = threadIdx.x;
  for (int i = t; i < NCLS * HID; i += 64) Wl[i] = w_lin[i];
  if (t < NCLS) bl[t] = b_lin[t];
  __syncthreads();

  const int r0 = (blockIdx.x * 64 + t) * 4;
  float acc[4][NCLS];
#pragma unroll
  for (int r = 0; r < 4; ++r)
#pragma unroll
    for (int c = 0; c < NCLS; ++c) acc[r][c] = bl[c];

  for (int k = 0; k < HID; k += 4) {
    float4 h0 = *(const float4*)(Hd + (size_t)(r0 + 0) * HID + k);
    float4 h1 = *(const float4*)(Hd + (size_t)(r0 + 1) * HID + k);
    float4 h2 = *(const float4*)(Hd + (size_t)(r0 + 2) * HID + k);
    float4 h3 = *(const float4*)(Hd + (size_t)(r0 + 3) * HID + k);
#pragma unroll
    for (int c = 0; c < NCLS; ++c) {
      float4 w4 = *(const float4*)&Wl[c * HID + k];
      acc[0][c] += h0.x * w4.x + h0.y * w4.y + h0.z * w4.z + h0.w * w4.w;
      acc[1][c] += h1.x * w4.x + h1.y * w4.y + h1.z * w4.z + h1.w * w4.w;
      acc[2][c] += h2.x * w4.x + h2.y * w4.y + h2.z * w4.z + h2.w * w4.w;
      acc[3][c] += h3.x * w4.x + h3.y * w4.y + h3.z * w4.z + h3.w * w4.w;
    }
  }

  float lse[4];
#pragma unroll
  for (int r = 0; r < 4; ++r) {
    float mx = acc[r][0];
#pragma unroll
    for (int c = 1; c < NCLS; ++c) mx = fmaxf(mx, acc[r][c]);
    float se = 0.f;
#pragma unroll
    for (int c = 0; c < NCLS; ++c) se += __expf(acc[r][c] - mx);
    lse[r] = mx + __logf(se);
  }
  const int b = r0 >> 9, s0 = r0 & 511;
#pragma unroll
  for (int c = 0; c < NCLS; ++c) {
    float4 o = make_float4(acc[0][c] - lse[0], acc[1][c] - lse[1],
                           acc[2][c] - lse[2], acc[3][c] - lse[3]);
    *(float4*)(out + (size_t)(b * NCLS + c) * SEQ + s0) = o;
  }
}

// ---------------- host ----------------
extern "C" void kernel_launch(void* const* d_in, const int* in_sizes, int n_in,
                              void* d_out, int out_size, void* d_ws, size_t ws_size,
                              hipStream_t stream) {
  const int*   inputs = (const int*)d_in[0];
  const float* emb    = (const float*)d_in[1];
  const float* w_ih   = (const float*)d_in[2];
  const float* w_hh   = (const float*)d_in[3];
  const float* b_ih   = (const float*)d_in[4];
  const float* b_hh   = (const float*)d_in[5];
  const float* w_lin  = (const float*)d_in[6];
  const float* b_lin  = (const float*)d_in[7];
  float* out = (float*)d_out;

  float* GI = (float*)d_ws;                          // 78.6 MB
  float* Hd = GI + (size_t)NROWS * G3;               // 26.2 MB
  uint8_t* M1 = (uint8_t*)(Hd + (size_t)NROWS * HID); // 2.46 MB (bit-packed)
  uint8_t* M2 = M1 + (size_t)M1_WORDS * 4;           // 0.82 MB

  uint32_t dk1a, dk1b, dk2a, dk2b;
  threefry2x32(0u, 42u, 0u, 0u, &dk1a, &dk1b);
  threefry2x32(0u, 42u, 0u, 1u, &dk2a, &dk2b);

  k_mask<<<(M1_WORDS + M2_WORDS) / 256, 256, 0, stream>>>(
      (uint32_t*)M1, (uint32_t*)M2, dk1a, dk1b, dk2a, dk2b);
  k_gi4<<<dim3(512, 3), 256, 0, stream>>>(inputs, emb, w_ih, b_ih, M1, GI);
  k_rnn7<<<BATCH, 1024, 0, stream>>>(GI, w_hh, b_hh, M2, Hd);
  k_out<<<256, 64, 0, stream>>>(Hd, w_lin, b_lin, out);
}

// Round 9
// 731.798 us; speedup vs baseline: 1.4777x; 1.1065x over previous
//
#include <hip/hip_runtime.h>
#include <hip/hip_bf16.h>
#include <cstdint>

#define BATCH 128
#define SEQ   512
#define EMB   300
#define HID   100
#define G3    300
#define NCLS  20
#define NROWS (SEQ * BATCH)

#define M1_WORDS 614400   // 128*512*300 / 32
#define M2_WORDS 204800   // 512*128*100 / 32

typedef __attribute__((ext_vector_type(4))) float f32x4;
typedef __attribute__((ext_vector_type(8))) short s16x8;

// ---------------- threefry2x32 (JAX-compatible, verified round 1) ----------------
__host__ __device__ __forceinline__ void threefry2x32(uint32_t k0, uint32_t k1,
                                                      uint32_t x0, uint32_t x1,
                                                      uint32_t* o0, uint32_t* o1) {
  uint32_t ks2 = k0 ^ k1 ^ 0x1BD11BDAu;
  x0 += k0; x1 += k1;
#define TFR(r) { x0 += x1; x1 = (x1 << (r)) | (x1 >> (32 - (r))); x1 ^= x0; }
  TFR(13) TFR(15) TFR(26) TFR(6)  x0 += k1;  x1 += ks2 + 1u;
  TFR(17) TFR(29) TFR(16) TFR(24) x0 += ks2; x1 += k0 + 2u;
  TFR(13) TFR(15) TFR(26) TFR(6)  x0 += k0;  x1 += k1 + 3u;
  TFR(17) TFR(29) TFR(16) TFR(24) x0 += k1;  x1 += ks2 + 4u;
  TFR(13) TFR(15) TFR(26) TFR(6)  x0 += ks2; x1 += k0 + 5u;
#undef TFR
  *o0 = x0; *o1 = x1;
}

__device__ __forceinline__ uint32_t rand_bits32(uint32_t ka, uint32_t kb, uint32_t flat) {
  uint32_t a, b;
  threefry2x32(ka, kb, 0u, flat, &a, &b);
  return a ^ b;
}

__device__ __forceinline__ short f2bf(float f) {   // RNE fp32->bf16
  union { float f; uint32_t u; } c; c.f = f;
  uint32_t u = c.u;
  return (short)((u + 0x7FFFu + ((u >> 16) & 1u)) >> 16);
}

// raw barrier: LDS-only drain, NO vmcnt(0) (the m97 barrier stall)
__device__ __forceinline__ void bar_lds() {
  __asm__ __volatile__("s_waitcnt lgkmcnt(0)" ::: "memory");
  __builtin_amdgcn_s_barrier();
  __asm__ __volatile__("" ::: "memory");
}

// ---------------- K0: precompute bit-packed dropout masks [unchanged] ----------------
__global__ __launch_bounds__(256) void k_mask(uint32_t* __restrict__ M1w,
                                              uint32_t* __restrict__ M2w,
                                              uint32_t k1a, uint32_t k1b,
                                              uint32_t k2a, uint32_t k2b) {
  const int i = blockIdx.x * 256 + threadIdx.x;
  uint32_t ka, kb, base;
  uint32_t* dst;
  if (i < M1_WORDS) { ka = k1a; kb = k1b; base = (uint32_t)i * 32u; dst = M1w + i; }
  else { ka = k2a; kb = k2b; base = (uint32_t)(i - M1_WORDS) * 32u; dst = M2w + (i - M1_WORDS); }
  uint32_t w = 0u;
#pragma unroll
  for (int j = 0; j < 32; ++j) {
    uint32_t bits = rand_bits32(ka, kb, base + (uint32_t)j);
    w |= ((~bits) >> 31) << j;
  }
  *dst = w;
}

// ---------------- K1 v5: MFMA bf16 GEMM for GI ----------------
// GI[s*128+b][n] = sum_k dropout1(emb[idx])[b][k] * w_ih[n][k] + b_ih[n]
// block 256 (4 waves, 2x2 wave grid, 64x64/wave), tile 128(m=b) x 128(n),
// grid (512 s, 3 n-tiles), K padded 300->320 (10 chunks of 32).
__global__ __launch_bounds__(256) void k_gi5(const int* __restrict__ inputs,
                                             const float* __restrict__ emb,
                                             const float* __restrict__ w_ih,
                                             const float* __restrict__ b_ih,
                                             const uint32_t* __restrict__ M1w,
                                             float* __restrict__ GI) {
  __shared__ short As[128 * 40];   // [b][k], stride 40 shorts = 80B (2-way banks)
  __shared__ short Bs[128 * 40];   // [n][k]
  __shared__ int idxs[128];
  const int t = threadIdx.x;
  const int s = blockIdx.x;
  const int n0 = blockIdx.y * 128;
  const int lane = t & 63, wave = t >> 6;
  const int wr = wave >> 1, wc = wave & 1;
  const int ml = lane & 15, quad = lane >> 4;
  const int row = t >> 1;      // staging: 0..127
  const int half = t & 1;      // staging: k-half of 16

  if (t < 128) idxs[t] = inputs[t * SEQ + s];
  __syncthreads();

  f32x4 acc[4][4];
#pragma unroll
  for (int i = 0; i < 4; ++i)
#pragma unroll
    for (int j = 0; j < 4; ++j) acc[i][j] = (f32x4){0.f, 0.f, 0.f, 0.f};

  const int myidx = idxs[row];
  const int nrow = n0 + row;

  for (int c = 0; c < 10; ++c) {
    const int kc = c * 32;
    const int e0 = kc + half * 16;
    // ---- stage A (gather + dropout1 + bf16) and B (w_ih + bf16) into regs ----
    float xa[16], xb[16];
#pragma unroll
    for (int j = 0; j < 16; ++j) { xa[j] = 0.f; xb[j] = 0.f; }
    if (e0 + 15 < 300) {
#pragma unroll
      for (int q4 = 0; q4 < 4; ++q4) {
        float4 v = *(const float4*)(emb + (size_t)myidx * EMB + e0 + q4 * 4);
        xa[q4 * 4 + 0] = v.x; xa[q4 * 4 + 1] = v.y; xa[q4 * 4 + 2] = v.z; xa[q4 * 4 + 3] = v.w;
      }
      if (nrow < 300) {
#pragma unroll
        for (int q4 = 0; q4 < 4; ++q4) {
          float4 v = *(const float4*)(w_ih + (size_t)nrow * EMB + e0 + q4 * 4);
          xb[q4 * 4 + 0] = v.x; xb[q4 * 4 + 1] = v.y; xb[q4 * 4 + 2] = v.z; xb[q4 * 4 + 3] = v.w;
        }
      }
    } else if (e0 < 300) {   // ragged tail (kc=288, half=0: e 288..299)
#pragma unroll
      for (int j = 0; j < 16; ++j) {
        int e = e0 + j;
        if (e < 300) {
          xa[j] = emb[(size_t)myidx * EMB + e];
          if (nrow < 300) xb[j] = w_ih[(size_t)nrow * EMB + e];
        }
      }
    }
    // dropout1 keep-bits (16 bits, possibly straddling a word)
    uint32_t base = (uint32_t)((row * SEQ + s) * EMB + e0);
    uint32_t mb = 0;
    if (e0 < 300) {
      uint64_t mw = (uint64_t)M1w[base >> 5] | ((uint64_t)M1w[(base >> 5) + 1] << 32);
      mb = (uint32_t)(mw >> (base & 31));
    }
    short sa[16], sb[16];
#pragma unroll
    for (int j = 0; j < 16; ++j) {
      float v = ((mb >> j) & 1u) ? xa[j] * 2.f : 0.f;
      sa[j] = f2bf(v);
      sb[j] = f2bf(xb[j]);
    }
    if (c > 0) __syncthreads();   // protect previous chunk's frag reads
    *(s16x8*)&As[row * 40 + half * 16 + 0] = *(s16x8*)&sa[0];
    *(s16x8*)&As[row * 40 + half * 16 + 8] = *(s16x8*)&sa[8];
    *(s16x8*)&Bs[row * 40 + half * 16 + 0] = *(s16x8*)&sb[0];
    *(s16x8*)&Bs[row * 40 + half * 16 + 8] = *(s16x8*)&sb[8];
    __syncthreads();
    // ---- MFMA: 4x4 tiles of 16x16 per wave ----
    s16x8 af[4], bf[4];
#pragma unroll
    for (int mt = 0; mt < 4; ++mt)
      af[mt] = *(const s16x8*)&As[(wr * 64 + mt * 16 + ml) * 40 + quad * 8];
#pragma unroll
    for (int nt = 0; nt < 4; ++nt)
      bf[nt] = *(const s16x8*)&Bs[(wc * 64 + nt * 16 + ml) * 40 + quad * 8];
#pragma unroll
    for (int mt = 0; mt < 4; ++mt)
#pragma unroll
      for (int nt = 0; nt < 4; ++nt)
        acc[mt][nt] = __builtin_amdgcn_mfma_f32_16x16x32_bf16(af[mt], bf[nt], acc[mt][nt], 0, 0, 0);
  }

  // ---- epilogue: C/D layout col=lane&15, row=quad*4+i ----
#pragma unroll
  for (int nt = 0; nt < 4; ++nt) {
    int n = n0 + wc * 64 + nt * 16 + ml;
    if (n < 300) {
      float bias = b_ih[n];
#pragma unroll
      for (int mt = 0; mt < 4; ++mt) {
#pragma unroll
        for (int i = 0; i < 4; ++i) {
          int brow = wr * 64 + mt * 16 + quad * 4 + i;
          GI[(size_t)(s * BATCH + brow) * G3 + n] = acc[mt][nt][i] + bias;
        }
      }
    }
  }
}

// ---------------- K2 v8: EXACT v7 skeleton, __syncthreads -> raw LDS barrier ----------
__global__ __launch_bounds__(1024, 4) void k_rnn8(const float* __restrict__ GI,
                                                  const float* __restrict__ w_hh,
                                                  const float* __restrict__ b_hh,
                                                  const uint8_t* __restrict__ M2,
                                                  float* __restrict__ Hd) {
  __shared__ float4 part[8][104];
  __shared__ float h_s[100];
  const int t = threadIdx.x, lane = t & 63, wave = t >> 6;
  const int q = wave >> 1, g = wave & 1;
  const int b = blockIdx.x;
  const int ulo = (lane < 36) ? lane : 35;
  const int u = g ? (64 + ulo) : lane;
  const bool dotstore = (g == 0) || (lane < 36);
  const int klo = (q < 4) ? q * 13 : 52 + (q - 4) * 12;

  const float* rowR = w_hh + (size_t)u * HID;
  const float* rowZ = w_hh + (size_t)(u + 100) * HID;
  const float* rowN = w_hh + (size_t)(u + 200) * HID;
  const float wr0 = rowR[klo + 0],  wr1 = rowR[klo + 1],  wr2 = rowR[klo + 2],
              wr3 = rowR[klo + 3],  wr4 = rowR[klo + 4],  wr5 = rowR[klo + 5],
              wr6 = rowR[klo + 6],  wr7 = rowR[klo + 7],  wr8 = rowR[klo + 8],
              wr9 = rowR[klo + 9],  wr10 = rowR[klo + 10], wr11 = rowR[klo + 11],
              wr12 = rowR[(klo + 12 < 100) ? (klo + 12) : 99];
  const float wz0 = rowZ[klo + 0],  wz1 = rowZ[klo + 1],  wz2 = rowZ[klo + 2],
              wz3 = rowZ[klo + 3],  wz4 = rowZ[klo + 4],  wz5 = rowZ[klo + 5],
              wz6 = rowZ[klo + 6],  wz7 = rowZ[klo + 7],  wz8 = rowZ[klo + 8],
              wz9 = rowZ[klo + 9],  wz10 = rowZ[klo + 10], wz11 = rowZ[klo + 11],
              wz12 = rowZ[(klo + 12 < 100) ? (klo + 12) : 99];
  const float wn0 = rowN[klo + 0],  wn1 = rowN[klo + 1],  wn2 = rowN[klo + 2],
              wn3 = rowN[klo + 3],  wn4 = rowN[klo + 4],  wn5 = rowN[klo + 5],
              wn6 = rowN[klo + 6],  wn7 = rowN[klo + 7],  wn8 = rowN[klo + 8],
              wn9 = rowN[klo + 9],  wn10 = rowN[klo + 10], wn11 = rowN[klo + 11],
              wn12 = rowN[(klo + 12 < 100) ? (klo + 12) : 99];

  const bool ew = (wave < 4) && (lane < 25);
  const int ue = wave * 25 + lane;   // 0..99 when ew
  float bR = 0.f, bZ = 0.f, bN = 0.f, gcR = 0.f, gcZ = 0.f, gcN = 0.f;
  uint8_t mc = 0;
  if (ew) {
    bR = b_hh[ue]; bZ = b_hh[100 + ue]; bN = b_hh[200 + ue];
    const float* g0 = GI + (size_t)b * G3;
    gcR = g0[ue]; gcZ = g0[100 + ue]; gcN = g0[200 + ue];
    mc = M2[(uint32_t)(b * HID + ue) >> 3];
  }

  if (t < 100) h_s[t] = 0.f;
  float hA = 0.f, hB = 0.f;
  __syncthreads();

#define RL(reg, L) __int_as_float(__builtin_amdgcn_readlane(__float_as_int(reg), (L)))
#define S1(HS, L, WR, WZ, WN) { float hk = RL(HS, L); \
    sR = fmaf(WR, hk, sR); sZ = fmaf(WZ, hk, sZ); sN = fmaf(WN, hk, sN); }
#define D12(HS, L0) \
  S1(HS, (L0) + 0,  wr0,  wz0,  wn0)  S1(HS, (L0) + 1,  wr1,  wz1,  wn1)  \
  S1(HS, (L0) + 2,  wr2,  wz2,  wn2)  S1(HS, (L0) + 3,  wr3,  wz3,  wn3)  \
  S1(HS, (L0) + 4,  wr4,  wz4,  wn4)  S1(HS, (L0) + 5,  wr5,  wz5,  wn5)  \
  S1(HS, (L0) + 6,  wr6,  wz6,  wn6)  S1(HS, (L0) + 7,  wr7,  wz7,  wn7)  \
  S1(HS, (L0) + 8,  wr8,  wz8,  wn8)  S1(HS, (L0) + 9,  wr9,  wz9,  wn9)  \
  S1(HS, (L0) + 10, wr10, wz10, wn10) S1(HS, (L0) + 11, wr11, wz11, wn11)
#define D13(HS, L0) D12(HS, L0) S1(HS, (L0) + 12, wr12, wz12, wn12)

  for (int s = 0; s < SEQ; ++s) {
    float gnR = 0.f, gnZ = 0.f, gnN = 0.f;
    uint8_t mn = 0;
    if (ew) {
      int sn = (s + 1 < SEQ) ? s + 1 : s;
      const float* gp = GI + (size_t)(sn * BATCH + b) * G3;
      gnR = gp[ue]; gnZ = gp[100 + ue]; gnN = gp[200 + ue];
      mn = M2[(uint32_t)((sn * BATCH + b) * HID + ue) >> 3];
    }

    float sR = 0.f, sZ = 0.f, sN = 0.f;
    switch (q) {
      case 0: { D13(hA, 0)  } break;
      case 1: { D13(hA, 13) } break;
      case 2: { D13(hA, 26) } break;
      case 3: { D13(hA, 39) } break;
      case 4: { D12(hA, 52) } break;
      case 5: { D12(hB, 0)  } break;
      case 6: { D12(hB, 12) } break;
      case 7: { D12(hB, 24) } break;
    }
    if (dotstore) part[q][u] = make_float4(sR, sZ, sN, 0.f);
    bar_lds();   // barrier 1: LDS drain only — no vmcnt(0)

    if (wave < 4) {
      if (lane < 25) {
        float4 p0 = part[0][ue], p1 = part[1][ue], p2 = part[2][ue], p3 = part[3][ue];
        float4 p4 = part[4][ue], p5 = part[5][ue], p6 = part[6][ue], p7 = part[7][ue];
        float hr = ((p0.x + p1.x) + (p2.x + p3.x)) + ((p4.x + p5.x) + (p6.x + p7.x)) + bR;
        float hz = ((p0.y + p1.y) + (p2.y + p3.y)) + ((p4.y + p5.y) + (p6.y + p7.y)) + bZ;
        float hn = ((p0.z + p1.z) + (p2.z + p3.z)) + ((p4.z + p5.z) + (p6.z + p7.z)) + bN;
        float r = 1.f / (1.f + __expf(-(gcR + hr)));
        float z = 1.f / (1.f + __expf(-(gcZ + hz)));
        float xn = gcN + r * hn;
        float e2 = __expf(2.f * fabsf(xn));
        float n = copysignf(1.f - 2.f / (e2 + 1.f), xn);   // overflow-safe tanh
        float hprev = h_s[ue];
        float hnew = (1.f - z) * n + z * hprev;
        uint32_t fl = (uint32_t)((s * BATCH + b) * HID + ue);
        float hd = ((mc >> (fl & 7)) & 1) ? hnew * 2.f : 0.f;
        Hd[(size_t)(b * SEQ + s) * HID + ue] = hd;   // store stays in flight (no drain)
        h_s[ue] = hnew;
      }
    }
    bar_lds();   // barrier 2: LDS drain only
    hA = h_s[lane];
    hB = h_s[64 + ulo];
    gcR = gnR; gcZ = gnZ; gcN = gnN; mc = mn;
  }
#undef D13
#undef D12
#undef S1
#undef RL
}

// ---------------- K3: logits + log_softmax [unchanged] ----------------
__global__ __launch_bounds__(64) void k_out(const float* __restrict__ Hd,
                                            const float* __restrict__ w_lin,
                                            const float* __restrict__ b_lin,
                                            float* __restrict__ out) {
  __shared__ float Wl[NCLS * HID];
  __shared__ float bl[NCLS];
  const int t = threadIdx.x;
  for (int i = t; i < NCLS * HID; i += 64) Wl[i] = w_lin[i];
  if (t < NCLS) bl[t] = b_lin[t];
  __syncthreads();

  const int r0 = (blockIdx.x * 64 + t) * 4;
  float acc[4][NCLS];
#pragma unroll
  for (int r = 0; r < 4; ++r)
#pragma unroll
    for (int c = 0; c < NCLS; ++c) acc[r][c] = bl[c];

  for (int k = 0; k < HID; k += 4) {
    float4 h0 = *(const float4*)(Hd + (size_t)(r0 + 0) * HID + k);
    float4 h1 = *(const float4*)(Hd + (size_t)(r0 + 1) * HID + k);
    float4 h2 = *(const float4*)(Hd + (size_t)(r0 + 2) * HID + k);
    float4 h3 = *(const float4*)(Hd + (size_t)(r0 + 3) * HID + k);
#pragma unroll
    for (int c = 0; c < NCLS; ++c) {
      float4 w4 = *(const float4*)&Wl[c * HID + k];
      acc[0][c] += h0.x * w4.x + h0.y * w4.y + h0.z * w4.z + h0.w * w4.w;
      acc[1][c] += h1.x * w4.x + h1.y * w4.y + h1.z * w4.z + h1.w * w4.w;
      acc[2][c] += h2.x * w4.x + h2.y * w4.y + h2.z * w4.z + h2.w * w4.w;
      acc[3][c] += h3.x * w4.x + h3.y * w4.y + h3.z * w4.z + h3.w * w4.w;
    }
  }

  float lse[4];
#pragma unroll
  for (int r = 0; r < 4; ++r) {
    float mx = acc[r][0];
#pragma unroll
    for (int c = 1; c < NCLS; ++c) mx = fmaxf(mx, acc[r][c]);
    float se = 0.f;
#pragma unroll
    for (int c = 0; c < NCLS; ++c) se += __expf(acc[r][c] - mx);
    lse[r] = mx + __logf(se);
  }
  const int b = r0 >> 9, s0 = r0 & 511;
#pragma unroll
  for (int c = 0; c < NCLS; ++c) {
    float4 o = make_float4(acc[0][c] - lse[0], acc[1][c] - lse[1],
                           acc[2][c] - lse[2], acc[3][c] - lse[3]);
    *(float4*)(out + (size_t)(b * NCLS + c) * SEQ + s0) = o;
  }
}

// ---------------- host ----------------
extern "C" void kernel_launch(void* const* d_in, const int* in_sizes, int n_in,
                              void* d_out, int out_size, void* d_ws, size_t ws_size,
                              hipStream_t stream) {
  const int*   inputs = (const int*)d_in[0];
  const float* emb    = (const float*)d_in[1];
  const float* w_ih   = (const float*)d_in[2];
  const float* w_hh   = (const float*)d_in[3];
  const float* b_ih   = (const float*)d_in[4];
  const float* b_hh   = (const float*)d_in[5];
  const float* w_lin  = (const float*)d_in[6];
  const float* b_lin  = (const float*)d_in[7];
  float* out = (float*)d_out;

  float* GI = (float*)d_ws;                          // 78.6 MB
  float* Hd = GI + (size_t)NROWS * G3;               // 26.2 MB
  uint8_t* M1 = (uint8_t*)(Hd + (size_t)NROWS * HID); // 2.46 MB (bit-packed)
  uint8_t* M2 = M1 + (size_t)M1_WORDS * 4;           // 0.82 MB

  uint32_t dk1a, dk1b, dk2a, dk2b;
  threefry2x32(0u, 42u, 0u, 0u, &dk1a, &dk1b);
  threefry2x32(0u, 42u, 0u, 1u, &dk2a, &dk2b);

  k_mask<<<(M1_WORDS + M2_WORDS) / 256, 256, 0, stream>>>(
      (uint32_t*)M1, (uint32_t*)M2, dk1a, dk1b, dk2a, dk2b);
  k_gi5<<<dim3(512, 3), 256, 0, stream>>>(inputs, emb, w_ih, b_ih, (const uint32_t*)M1, GI);
  k_rnn8<<<BATCH, 1024, 0, stream>>>(GI, w_hh, b_hh, M2, Hd);
  k_out<<<256, 64, 0, stream>>>(Hd, w_lin, b_lin, out);
}